// Round 9
// baseline (134.808 us; speedup 1.0000x reference)
//
#include <hip/hip_runtime.h>

// KANLayer via INT8 GEMM, i32 accumulation, per-plane scales (r8 scheme,
// absmax 0.41 verified). r9 change: B removed from LDS — fold_q writes B in
// MFMA-fragment-packed order ([g][kt][lane][16B]) so gemm loads B-frags as
// coalesced 1KB global_load_dwordx4 from L2 (per-XCD-resident panel).
// LDS carries only A (32 KiB dbuf). BM=BN=128, BK=128, 4 waves 2x2.

#define IN_F   1024
#define OUT_F  1024
#define M_DIM  8192
#define N_DIM  1024
#define KP     9
#define K_DIM  (IN_F * KP)     // 9216
#define BK     128
#define NTILES (K_DIM / BK)    // 72
#define NKT    (K_DIM / 64)    // 144 (B packed kt-unit = 64)

typedef __attribute__((ext_vector_type(4)))  int   i32x4;
typedef __attribute__((ext_vector_type(4)))  float f32x4;
typedef __attribute__((ext_vector_type(16))) char  char16v;

// quantization constants (r8, verified)
#define SX   (6.0f / 127.0f)
#define ISX  (127.0f / 6.0f)
#define ISL  (16129.0f / 3.0f)
#define TB   (0.7f / 127.0f)
#define ITB  (127.0f / 0.7f)
#define ITL  (16129.0f / 0.35f)
#define ITE  (127.0f / 1.4f)

__device__ __constant__ float SCALES[9] = {
    4.2f / 16129.0f,
    2.1f / 2048383.0f,
    2.1f / 2048383.0f,
    1.4f / 16129.0f,
    0.7f / 16129.0f,
    0.7f / 16129.0f,
    0.7f / 16129.0f,
    0.7f / 16129.0f,
    1.4f / 16129.0f
};

__device__ inline float clampf(float v, float lo, float hi) {
    return fminf(fmaxf(v, lo), hi);
}

// --------------------------------------------------------------------------
// expand_q: x -> Aq[M][9216] i8 row-major (unchanged from r8).
// --------------------------------------------------------------------------
__global__ void expand_q(const float* __restrict__ x, signed char* __restrict__ Aq) {
    int idx = blockIdx.x * 256 + threadIdx.x;   // m*64 + i16
    int m = idx >> 6, i16 = idx & 63;
    const float4* xp = reinterpret_cast<const float4*>(x + ((size_t)m << 10) + i16 * 16);
    float v[16];
    #pragma unroll
    for (int q = 0; q < 4; ++q) {
        float4 f = xp[q];
        v[4*q] = f.x; v[4*q+1] = f.y; v[4*q+2] = f.z; v[4*q+3] = f.w;
    }
    signed char out[9][16];
    #pragma unroll
    for (int e = 0; e < 16; ++e) {
        float xe = v[e];
        float xh = clampf(rintf(xe * ISX), -127.f, 127.f);
        float xl = xe - xh * SX;
        out[0][e] = (signed char)(int)xh;
        out[1][e] = (signed char)(int)xh;
        out[2][e] = (signed char)(int)clampf(rintf(xl * ISL), -127.f, 127.f);
        float xc = clampf(xe, -1.f, 1.f);
        #pragma unroll
        for (int j = 0; j < 6; ++j) {
            float t = -1.f + 0.4f * (float)j;
            float h = fmaxf(1.f - fabsf((xc - t) * 2.5f), 0.f);
            out[3 + j][e] = (signed char)(int)rintf(h * 127.f);
        }
    }
    size_t base = (size_t)m * K_DIM + i16 * 16;
    #pragma unroll
    for (int p = 0; p < 9; ++p) {
        char16v pk;
        #pragma unroll
        for (int e = 0; e < 16; ++e) pk[e] = out[p][e];
        *reinterpret_cast<char16v*>(Aq + base + (size_t)p * 1024) = pk;
    }
}

// --------------------------------------------------------------------------
// fold_q: spline/base weights -> Bp FRAGMENT-PACKED i8:
//   Bp[((g*144 + kt)*64 + lane)*16 + byte], where the verified i8 fragment
//   mapping is lane -> col g*16 + (lane&15), k = kt*64 + (lane>>4)*16 + byte.
//   Thread (o, i4) covers col o, k = p*1024 + i4*4 .. +3:
//     g = o>>4; kt = p*16 + (i4>>4); lane = (o&15) + 16*((i4>>2)&3);
//     byte = (i4&3)*4.
// --------------------------------------------------------------------------
__global__ void fold_q(const float* __restrict__ sw, const float* __restrict__ bw,
                       signed char* __restrict__ Bp) {
    int idx = blockIdx.x * 256 + threadIdx.x;   // o*256 + i4
    int o = idx >> 8, i4 = idx & 255;
    signed char out[9][4];
    #pragma unroll
    for (int e = 0; e < 4; ++e) {
        int i = i4 * 4 + e;
        const float4* p = reinterpret_cast<const float4*>(sw + (size_t)(o * 1024 + i) * 12);
        float4 a = p[0];
        float4 b = p[1];
        float4 c = p[2];
        float w = bw[o * 1024 + i];
        float wh = clampf(rintf(w * ITB), -127.f, 127.f);
        float wl = w - wh * TB;
        out[0][e] = (signed char)(int)wh;
        out[1][e] = (signed char)(int)clampf(rintf(wl * ITL), -127.f, 127.f);
        out[2][e] = (signed char)(int)wh;
        out[3][e] = (signed char)(int)clampf(rintf((a.x + a.y + a.z + a.w) * ITE), -127.f, 127.f);
        out[4][e] = (signed char)(int)clampf(rintf(b.x * ITB), -127.f, 127.f);
        out[5][e] = (signed char)(int)clampf(rintf(b.y * ITB), -127.f, 127.f);
        out[6][e] = (signed char)(int)clampf(rintf(b.z * ITB), -127.f, 127.f);
        out[7][e] = (signed char)(int)clampf(rintf(b.w * ITB), -127.f, 127.f);
        out[8][e] = (signed char)(int)clampf(rintf((c.x + c.y + c.z + c.w) * ITE), -127.f, 127.f);
    }
    const int g      = o >> 4;
    const int lane   = (o & 15) + 16 * ((i4 >> 2) & 3);
    const int byteof = (i4 & 3) * 4;
    #pragma unroll
    for (int p = 0; p < 9; ++p) {
        int kt = p * 16 + (i4 >> 4);
        char4 pk;
        pk.x = out[p][0]; pk.y = out[p][1]; pk.z = out[p][2]; pk.w = out[p][3];
        *reinterpret_cast<char4*>(Bp + (((size_t)g * NKT + kt) * 64 + lane) * 16 + byteof) = pk;
    }
}

// --------------------------------------------------------------------------
// i8 GEMM, A via LDS dbuf (XOR swizzle, verified 0-conflict in r8), B via
// coalesced fragment loads from packed layout. bx = blockIdx.x & 7: XCD
// round-robin dispatch pins one bx (1.2 MB B-panel) per XCD -> L2-resident.
// --------------------------------------------------------------------------
__global__ __launch_bounds__(256, 2) void gemm_q(
        const signed char* __restrict__ Aq,   // [M][9216] i8 row-major
        const signed char* __restrict__ Bp,   // fragment-packed
        float* __restrict__ C) {              // [M][N] f32
    __shared__ __align__(16) signed char As[2][128 * BK];   // 2 x 16 KiB

    const int tid  = threadIdx.x;
    const int wave = tid >> 6;
    const int lane = tid & 63;
    const int wr   = wave >> 1;   // 0..1 (M)
    const int wc   = wave & 1;    // 0..1 (N)

    const int bx   = blockIdx.x & 7;   // N tile — identity: one bx per XCD
    const int by   = blockIdx.x >> 3;  // M tile, 0..63

    // A staging: inst u covers rows u*32 + (tid>>3); source col pre-swizzled
    const int srow  = tid >> 3;
    const int scolb = ((tid & 7) * 16) ^ ((srow & 7) << 4);

#define STAGE(BUF, T) do {                                                      \
    int kt_ = ((T) < NTILES ? (T) : NTILES - 1) * BK;                           \
    _Pragma("unroll")                                                           \
    for (int u = 0; u < 4; ++u) {                                               \
        const signed char* ga_ = Aq + (size_t)(by * 128 + u * 32 + srow) * K_DIM + kt_ + scolb; \
        __builtin_amdgcn_global_load_lds(                                       \
            (const __attribute__((address_space(1))) void*)ga_,                 \
            (__attribute__((address_space(3))) void*)(As[BUF] + u * 4096 + wave * 1024), 16, 0, 0); \
    }                                                                           \
} while (0)

    i32x4 acci[4][4];
    f32x4 accf[4][4];
    #pragma unroll
    for (int m2 = 0; m2 < 4; ++m2)
        #pragma unroll
        for (int n2 = 0; n2 < 4; ++n2) {
            acci[m2][n2] = (i32x4){0, 0, 0, 0};
            accf[m2][n2] = (f32x4){0.f, 0.f, 0.f, 0.f};
        }

    // per-wave B base: g0 = bx*8 + wc*4; + lane chunk
    const size_t bwv = ((size_t)(bx * 8 + wc * 4) * NKT) * 1024 + (size_t)lane * 16;

    STAGE(0, 0);

    for (int t = 0; t < NTILES; ++t) {
        const int cur = t & 1;
        __syncthreads();              // vmcnt(0)+barrier: stage(t) published
        STAGE(cur ^ 1, t + 1);        // prefetch next A tile (clamped at end)

        // B fragments: coalesced 1KB loads from L2-resident packed panel
        i32x4 bf[8];
        #pragma unroll
        for (int n2 = 0; n2 < 4; ++n2)
            #pragma unroll
            for (int kk = 0; kk < 2; ++kk)
                bf[n2 * 2 + kk] = *reinterpret_cast<const i32x4*>(
                    Bp + bwv + ((size_t)n2 * NKT + 2 * t + kk) * 1024);

        // A fragments from LDS (swizzled; r8-verified pattern)
        i32x4 af[8];
        #pragma unroll
        for (int m2 = 0; m2 < 4; ++m2)
            #pragma unroll
            for (int kk = 0; kk < 2; ++kk) {
                int row = wr * 64 + m2 * 16 + (lane & 15);
                int off = row * BK + ((kk * 64 + (lane >> 4) * 16) ^ ((row & 7) << 4));
                af[m2 * 2 + kk] = *reinterpret_cast<const i32x4*>(&As[cur][off]);
            }

        __builtin_amdgcn_s_setprio(1);
        #pragma unroll
        for (int kk = 0; kk < 2; ++kk)          // kk-outer: kk=1 loads hide
            #pragma unroll
            for (int m2 = 0; m2 < 4; ++m2)
                #pragma unroll
                for (int n2 = 0; n2 < 4; ++n2)
                    acci[m2][n2] = __builtin_amdgcn_mfma_i32_16x16x64_i8(
                        af[m2 * 2 + kk], bf[n2 * 2 + kk], acci[m2][n2], 0, 0, 0);
        __builtin_amdgcn_s_setprio(0);

        if ((t & 7) == 7) {           // plane boundary: flush i32 -> f32
            float s = SCALES[t >> 3];
            #pragma unroll
            for (int m2 = 0; m2 < 4; ++m2)
                #pragma unroll
                for (int n2 = 0; n2 < 4; ++n2) {
                    #pragma unroll
                    for (int r = 0; r < 4; ++r)
                        accf[m2][n2][r] += s * (float)acci[m2][n2][r];
                    acci[m2][n2] = (i32x4){0, 0, 0, 0};
                }
        }
    }

    // epilogue: C/D layout col = lane&15, row = (lane>>4)*4 + r (verified)
    #pragma unroll
    for (int m2 = 0; m2 < 4; ++m2)
        #pragma unroll
        for (int n2 = 0; n2 < 4; ++n2) {
            const int row = by * 128 + wr * 64 + m2 * 16 + ((lane >> 4) << 2);
            const int col = bx * 128 + wc * 64 + n2 * 16 + (lane & 15);
            #pragma unroll
            for (int r = 0; r < 4; ++r)
                C[(size_t)(row + r) * N_DIM + col] = accf[m2][n2][r];
        }
#undef STAGE
}

// --------------------------------------------------------------------------
extern "C" void kernel_launch(void* const* d_in, const int* in_sizes, int n_in,
                              void* d_out, int out_size, void* d_ws, size_t ws_size,
                              hipStream_t stream) {
    const float* x  = (const float*)d_in[0];   // (4,2048,1024) f32
    const float* sw = (const float*)d_in[1];   // (1024,1024,12) f32
    const float* bw = (const float*)d_in[2];   // (1024,1024) f32
    float* out = (float*)d_out;                // (4,2048,1024) f32

    signed char* Aq = (signed char*)d_ws;                          // 75.5 MB
    signed char* Bp = (signed char*)d_ws + (size_t)M_DIM * K_DIM;  // 9.0 MB packed

    expand_q<<<(M_DIM * 64) / 256, 256, 0, stream>>>(x, Aq);
    fold_q<<<(OUT_F * 256) / 256, 256, 0, stream>>>(sw, bw, Bp);
    gemm_q<<<(M_DIM / 128) * (N_DIM / 128), 256, 0, stream>>>(Aq, Bp, out);
}

// Round 10
// 121.118 us; speedup vs baseline: 1.1130x; 1.1130x over previous
//
#include <hip/hip_runtime.h>

// KANLayer via INT8 GEMM, i32 accumulation, per-plane scales (r8 scheme,
// absmax 0.41 verified). r10 = r9 + two fixes:
//   (1) r8's XCD swizzle restored (contiguous by-strip per XCD -> A fetched
//       once; r9's identity mapping caused 8x A re-fetch, FETCH 300 MB).
//   (2) B fragments double-buffered in registers (bfA/bfB, unroll-2 loop)
//       -> L2 latency hidden a full tile ahead.
// B stays fragment-packed ([g][kt][lane][16B]) and loaded coalesced 1KB
// per wave directly from global (no LDS for B). LDS = A only, 32 KiB dbuf.

#define IN_F   1024
#define OUT_F  1024
#define M_DIM  8192
#define N_DIM  1024
#define KP     9
#define K_DIM  (IN_F * KP)     // 9216
#define BK     128
#define NTILES (K_DIM / BK)    // 72
#define NKT    (K_DIM / 64)    // 144 (B packed kt-unit = 64)

typedef __attribute__((ext_vector_type(4)))  int   i32x4;
typedef __attribute__((ext_vector_type(4)))  float f32x4;
typedef __attribute__((ext_vector_type(16))) char  char16v;

// quantization constants (r8, verified)
#define SX   (6.0f / 127.0f)
#define ISX  (127.0f / 6.0f)
#define ISL  (16129.0f / 3.0f)
#define TB   (0.7f / 127.0f)
#define ITB  (127.0f / 0.7f)
#define ITL  (16129.0f / 0.35f)
#define ITE  (127.0f / 1.4f)

__device__ __constant__ float SCALES[9] = {
    4.2f / 16129.0f,
    2.1f / 2048383.0f,
    2.1f / 2048383.0f,
    1.4f / 16129.0f,
    0.7f / 16129.0f,
    0.7f / 16129.0f,
    0.7f / 16129.0f,
    0.7f / 16129.0f,
    1.4f / 16129.0f
};

__device__ inline float clampf(float v, float lo, float hi) {
    return fminf(fmaxf(v, lo), hi);
}

// --------------------------------------------------------------------------
// expand_q: x -> Aq[M][9216] i8 row-major (unchanged from r8).
// --------------------------------------------------------------------------
__global__ void expand_q(const float* __restrict__ x, signed char* __restrict__ Aq) {
    int idx = blockIdx.x * 256 + threadIdx.x;   // m*64 + i16
    int m = idx >> 6, i16 = idx & 63;
    const float4* xp = reinterpret_cast<const float4*>(x + ((size_t)m << 10) + i16 * 16);
    float v[16];
    #pragma unroll
    for (int q = 0; q < 4; ++q) {
        float4 f = xp[q];
        v[4*q] = f.x; v[4*q+1] = f.y; v[4*q+2] = f.z; v[4*q+3] = f.w;
    }
    signed char out[9][16];
    #pragma unroll
    for (int e = 0; e < 16; ++e) {
        float xe = v[e];
        float xh = clampf(rintf(xe * ISX), -127.f, 127.f);
        float xl = xe - xh * SX;
        out[0][e] = (signed char)(int)xh;
        out[1][e] = (signed char)(int)xh;
        out[2][e] = (signed char)(int)clampf(rintf(xl * ISL), -127.f, 127.f);
        float xc = clampf(xe, -1.f, 1.f);
        #pragma unroll
        for (int j = 0; j < 6; ++j) {
            float t = -1.f + 0.4f * (float)j;
            float h = fmaxf(1.f - fabsf((xc - t) * 2.5f), 0.f);
            out[3 + j][e] = (signed char)(int)rintf(h * 127.f);
        }
    }
    size_t base = (size_t)m * K_DIM + i16 * 16;
    #pragma unroll
    for (int p = 0; p < 9; ++p) {
        char16v pk;
        #pragma unroll
        for (int e = 0; e < 16; ++e) pk[e] = out[p][e];
        *reinterpret_cast<char16v*>(Aq + base + (size_t)p * 1024) = pk;
    }
}

// --------------------------------------------------------------------------
// fold_q: weights -> Bp FRAGMENT-PACKED i8 (r9 layout, verified):
//   Bp[((g*144 + kt)*64 + lane)*16 + byte]; lane -> col g*16 + (lane&15),
//   k = kt*64 + (lane>>4)*16 + byte.
// --------------------------------------------------------------------------
__global__ void fold_q(const float* __restrict__ sw, const float* __restrict__ bw,
                       signed char* __restrict__ Bp) {
    int idx = blockIdx.x * 256 + threadIdx.x;   // o*256 + i4
    int o = idx >> 8, i4 = idx & 255;
    signed char out[9][4];
    #pragma unroll
    for (int e = 0; e < 4; ++e) {
        int i = i4 * 4 + e;
        const float4* p = reinterpret_cast<const float4*>(sw + (size_t)(o * 1024 + i) * 12);
        float4 a = p[0];
        float4 b = p[1];
        float4 c = p[2];
        float w = bw[o * 1024 + i];
        float wh = clampf(rintf(w * ITB), -127.f, 127.f);
        float wl = w - wh * TB;
        out[0][e] = (signed char)(int)wh;
        out[1][e] = (signed char)(int)clampf(rintf(wl * ITL), -127.f, 127.f);
        out[2][e] = (signed char)(int)wh;
        out[3][e] = (signed char)(int)clampf(rintf((a.x + a.y + a.z + a.w) * ITE), -127.f, 127.f);
        out[4][e] = (signed char)(int)clampf(rintf(b.x * ITB), -127.f, 127.f);
        out[5][e] = (signed char)(int)clampf(rintf(b.y * ITB), -127.f, 127.f);
        out[6][e] = (signed char)(int)clampf(rintf(b.z * ITB), -127.f, 127.f);
        out[7][e] = (signed char)(int)clampf(rintf(b.w * ITB), -127.f, 127.f);
        out[8][e] = (signed char)(int)clampf(rintf((c.x + c.y + c.z + c.w) * ITE), -127.f, 127.f);
    }
    const int g      = o >> 4;
    const int lane   = (o & 15) + 16 * ((i4 >> 2) & 3);
    const int byteof = (i4 & 3) * 4;
    #pragma unroll
    for (int p = 0; p < 9; ++p) {
        int kt = p * 16 + (i4 >> 4);
        char4 pk;
        pk.x = out[p][0]; pk.y = out[p][1]; pk.z = out[p][2]; pk.w = out[p][3];
        *reinterpret_cast<char4*>(Bp + (((size_t)g * NKT + kt) * 64 + lane) * 16 + byteof) = pk;
    }
}

// --------------------------------------------------------------------------
// i8 GEMM: A via LDS dbuf (XOR swizzle), B via reg-dbuf coalesced fragment
// loads. r8 XCD swizzle: XCD c covers by in [c*8, c*8+8) (A fetched once
// globally) and all bx (per-K-slice B working set ~256 KB, lockstep-hot).
// --------------------------------------------------------------------------
__global__ __launch_bounds__(256, 2) void gemm_q(
        const signed char* __restrict__ Aq,   // [M][9216] i8 row-major
        const signed char* __restrict__ Bp,   // fragment-packed
        float* __restrict__ C) {              // [M][N] f32
    __shared__ __align__(16) signed char As[2][128 * BK];   // 2 x 16 KiB

    const int tid  = threadIdx.x;
    const int wave = tid >> 6;
    const int lane = tid & 63;
    const int wr   = wave >> 1;   // 0..1 (M)
    const int wc   = wave & 1;    // 0..1 (N)

    // r8 XCD swizzle (bijective, nwg = 512)
    const int orig = blockIdx.x;
    const int wg   = (orig & 7) * 64 + (orig >> 3);
    const int bx   = wg & 7;      // N tile (BN=128)
    const int by   = wg >> 3;     // M tile (BM=128), 0..63

    // A staging: inst u covers rows u*32 + (tid>>3); source col pre-swizzled
    const int srow  = tid >> 3;
    const int scolb = ((tid & 7) * 16) ^ ((srow & 7) << 4);

#define STAGE(BUF, T) do {                                                      \
    int kt_ = ((T) < NTILES ? (T) : NTILES - 1) * BK;                           \
    _Pragma("unroll")                                                           \
    for (int u = 0; u < 4; ++u) {                                               \
        const signed char* ga_ = Aq + (size_t)(by * 128 + u * 32 + srow) * K_DIM + kt_ + scolb; \
        __builtin_amdgcn_global_load_lds(                                       \
            (const __attribute__((address_space(1))) void*)ga_,                 \
            (__attribute__((address_space(3))) void*)(As[BUF] + u * 4096 + wave * 1024), 16, 0, 0); \
    }                                                                           \
} while (0)

// B fragment load for tile T into 8 named regs (coalesced 1KB/inst from L2)
#define LOADB(BF, T) do {                                                       \
    int tt_ = ((T) < NTILES ? (T) : NTILES - 1);                                \
    _Pragma("unroll")                                                           \
    for (int n2 = 0; n2 < 4; ++n2)                                              \
        _Pragma("unroll")                                                       \
        for (int kk = 0; kk < 2; ++kk)                                          \
            BF[n2 * 2 + kk] = *reinterpret_cast<const i32x4*>(                  \
                Bp + bwv + ((size_t)n2 * NKT + 2 * tt_ + kk) * 1024);           \
} while (0)

// A fragments from LDS + 32 MFMAs against BF
#define COMPUTE(CUR, BF) do {                                                   \
    i32x4 af[8];                                                                \
    _Pragma("unroll")                                                           \
    for (int m2 = 0; m2 < 4; ++m2)                                              \
        _Pragma("unroll")                                                       \
        for (int kk = 0; kk < 2; ++kk) {                                        \
            int row = wr * 64 + m2 * 16 + (lane & 15);                          \
            int off = row * BK + ((kk * 64 + (lane >> 4) * 16) ^ ((row & 7) << 4)); \
            af[m2 * 2 + kk] = *reinterpret_cast<const i32x4*>(&As[CUR][off]);   \
        }                                                                       \
    __builtin_amdgcn_s_setprio(1);                                              \
    _Pragma("unroll")                                                           \
    for (int kk = 0; kk < 2; ++kk)                                              \
        _Pragma("unroll")                                                       \
        for (int m2 = 0; m2 < 4; ++m2)                                          \
            _Pragma("unroll")                                                   \
            for (int n2 = 0; n2 < 4; ++n2)                                      \
                acci[m2][n2] = __builtin_amdgcn_mfma_i32_16x16x64_i8(           \
                    af[m2 * 2 + kk], BF[n2 * 2 + kk], acci[m2][n2], 0, 0, 0);   \
    __builtin_amdgcn_s_setprio(0);                                              \
} while (0)

    i32x4 acci[4][4];
    f32x4 accf[4][4];
    #pragma unroll
    for (int m2 = 0; m2 < 4; ++m2)
        #pragma unroll
        for (int n2 = 0; n2 < 4; ++n2) {
            acci[m2][n2] = (i32x4){0, 0, 0, 0};
            accf[m2][n2] = (f32x4){0.f, 0.f, 0.f, 0.f};
        }

    // per-wave B base: groups g0 = bx*8 + wc*4 .. +3
    const size_t bwv = ((size_t)(bx * 8 + wc * 4) * NKT) * 1024 + (size_t)lane * 16;

    i32x4 bfA[8], bfB[8];
    STAGE(0, 0);
    LOADB(bfA, 0);

    #pragma unroll 1
    for (int i = 0; i < NTILES / 2; ++i) {
        // t = 2i (even; never a flush tile)
        __syncthreads();              // publishes STAGE(2i)
        STAGE(1, 2 * i + 1);
        LOADB(bfB, 2 * i + 1);        // consume next half; in flight ~1 tile
        COMPUTE(0, bfA);
        // t = 2i+1
        __syncthreads();              // publishes STAGE(2i+1)
        STAGE(0, 2 * i + 2);
        LOADB(bfA, 2 * i + 2);        // WAR on bfA: ordered after COMPUTE above
        COMPUTE(1, bfB);
        if ((i & 3) == 3) {           // t = 2i+1 ≡ 7 mod 8: plane flush
            float s = SCALES[(2 * i + 1) >> 3];
            #pragma unroll
            for (int m2 = 0; m2 < 4; ++m2)
                #pragma unroll
                for (int n2 = 0; n2 < 4; ++n2) {
                    #pragma unroll
                    for (int r = 0; r < 4; ++r)
                        accf[m2][n2][r] += s * (float)acci[m2][n2][r];
                    acci[m2][n2] = (i32x4){0, 0, 0, 0};
                }
        }
    }

    // epilogue: C/D layout col = lane&15, row = (lane>>4)*4 + r (verified)
    #pragma unroll
    for (int m2 = 0; m2 < 4; ++m2)
        #pragma unroll
        for (int n2 = 0; n2 < 4; ++n2) {
            const int row = by * 128 + wr * 64 + m2 * 16 + ((lane >> 4) << 2);
            const int col = bx * 128 + wc * 64 + n2 * 16 + (lane & 15);
            #pragma unroll
            for (int r = 0; r < 4; ++r)
                C[(size_t)(row + r) * N_DIM + col] = accf[m2][n2][r];
        }
#undef STAGE
#undef LOADB
#undef COMPUTE
}

// --------------------------------------------------------------------------
extern "C" void kernel_launch(void* const* d_in, const int* in_sizes, int n_in,
                              void* d_out, int out_size, void* d_ws, size_t ws_size,
                              hipStream_t stream) {
    const float* x  = (const float*)d_in[0];   // (4,2048,1024) f32
    const float* sw = (const float*)d_in[1];   // (1024,1024,12) f32
    const float* bw = (const float*)d_in[2];   // (1024,1024) f32
    float* out = (float*)d_out;                // (4,2048,1024) f32

    signed char* Aq = (signed char*)d_ws;                          // 75.5 MB
    signed char* Bp = (signed char*)d_ws + (size_t)M_DIM * K_DIM;  // 9.0 MB packed

    expand_q<<<(M_DIM * 64) / 256, 256, 0, stream>>>(x, Aq);
    fold_q<<<(OUT_F * 256) / 256, 256, 0, stream>>>(sw, bw, Bp);
    gemm_q<<<(M_DIM / 128) * (N_DIM / 128), 256, 0, stream>>>(Aq, Bp, out);
}